// Round 5
// baseline (1070.973 us; speedup 1.0000x reference)
//
#include <hip/hip_runtime.h>
#include <hip/hip_bf16.h>

// DecoderBlock: h_t = tanh(x_t @ U + h_{t-1} @ V + b). BZ=256,SEQ=512,HID=256.
//
// prep_W : U,V fp32 -> bf16 frag-ordered chunks (128 KB each).
// xu_gemm: XU^T-style MFMA GEMM (A=U^T frags in regs, B=x^T from LDS).
//          Writes bf16 XU+bias into the FIRST 512B of each 1KB h-row slot of
//          the decoder output region (in-place, consumed before h overwrite).
// rnn_rec: 16 WGs x 256 thr (4 waves). C^T = V^T @ h^T on MFMA; V^T frags in
//          regs/AGPRs; h bf16 in LDS (33-chunk padded rows -> conflict-free);
//          XU prefetched 4-deep from global; 1 barrier/step.

#define SEQn 512
#define HIDn 256
#define CHS  33   // padded chunk stride per row (32 data chunks of 16B + 1 pad)

typedef __attribute__((ext_vector_type(4))) float  floatx4;
typedef __attribute__((ext_vector_type(8))) short  short8;
typedef __attribute__((ext_vector_type(4))) short  shortx4;

__device__ __forceinline__ short f2bf(float f) {
    __hip_bfloat16 h = __float2bfloat16(f);
    return *reinterpret_cast<short*>(&h);
}
__device__ __forceinline__ float bf2f(unsigned int u16) {
    unsigned int v = u16 << 16;
    return __builtin_bit_cast(float, v);
}

// ---------------------------------------------------------------------------
// ws[((kb*4+q)*256 + col)*8 + j] = W[kb*32 + q*8 + j][col]  (bf16)
// Serves as: B-frag (k x n=col) AND A-frag of W^T (m=col x k).
// ---------------------------------------------------------------------------
__global__ void prep_W(const float* __restrict__ U, const float* __restrict__ V,
                       short* __restrict__ wsU, short* __restrict__ wsV) {
    int idx = blockIdx.x * 256 + threadIdx.x;   // 0..8191
    int col = idx & 255;
    int q   = (idx >> 8) & 3;
    int kb  = idx >> 10;
    int k0  = kb * 32 + q * 8;
    short8 cu, cv;
    #pragma unroll
    for (int j = 0; j < 8; j++) {
        cu[j] = f2bf(U[(size_t)(k0 + j) * 256 + col]);
        cv[j] = f2bf(V[(size_t)(k0 + j) * 256 + col]);
    }
    *(short8*)(wsU + (size_t)idx * 8) = cu;
    *(short8*)(wsV + (size_t)idx * 8) = cv;
}

// ---------------------------------------------------------------------------
// GEMM: computes XU[m][col] = x[m]@U[:,col] + b[col], m = 64-row block tile.
// Transposed MFMA: a = U^T frag (m-dim = XU cols, regs), b = x^T frag (n-dim
// = x rows, LDS). Wave w owns cols [64w,64w+64) (4 m-tiles); 4 n-tiles.
// Output: bf16 at byte  outB + m*1024 + col*2   (first 512B of h-row slot).
// ---------------------------------------------------------------------------
__global__ __launch_bounds__(256, 2)
void xu_gemm(const float* __restrict__ X, const short* __restrict__ wsU,
             const float* __restrict__ bias, char* __restrict__ outB)
{
    __shared__ short As[64 * CHS * 8];   // 64 rows x 33 chunks x 8 bf16

    const int tid = threadIdx.x;
    const int w   = tid >> 6;
    const int l   = tid & 63;
    const int lr  = l & 15;
    const int q   = l >> 4;
    const int m0  = blockIdx.x * 64;

    // U^T A-frags, register/AGPR-resident: 4 m-tiles x 8 kb.
    short8 uf[4][8];
    #pragma unroll
    for (int i = 0; i < 4; i++)
        #pragma unroll
        for (int kb = 0; kb < 8; kb++)
            uf[i][kb] = *(const short8*)(wsU +
                ((size_t)(kb * 4 + q) * 256 + 64 * w + 16 * i + lr) * 8);

    // stage x tile: 64 rows x 32 chunks, bf16, padded rows.
    #pragma unroll
    for (int j = 0; j < 8; j++) {
        int ci  = j * 256 + tid;         // 0..2047
        int row = ci >> 5;
        int c   = ci & 31;
        const float* g = X + (size_t)(m0 + row) * 256 + c * 8;
        float4 g0 = *(const float4*)g;
        float4 g1 = *(const float4*)(g + 4);
        short8 s = {f2bf(g0.x), f2bf(g0.y), f2bf(g0.z), f2bf(g0.w),
                    f2bf(g1.x), f2bf(g1.y), f2bf(g1.z), f2bf(g1.w)};
        *(short8*)&As[(row * CHS + c) * 8] = s;
    }
    __syncthreads();

    floatx4 acc[4][4];
    #pragma unroll
    for (int i = 0; i < 4; i++)
        #pragma unroll
        for (int j = 0; j < 4; j++)
            acc[i][j] = (floatx4){0.f, 0.f, 0.f, 0.f};

    #pragma unroll
    for (int kb = 0; kb < 8; kb++) {
        #pragma unroll
        for (int j = 0; j < 4; j++) {
            short8 xf = *(const short8*)&As[((16 * j + lr) * CHS + 4 * kb + q) * 8];
            #pragma unroll
            for (int i = 0; i < 4; i++)
                acc[i][j] = __builtin_amdgcn_mfma_f32_16x16x32_bf16(
                    uf[i][kb], xf, acc[i][j], 0, 0, 0);
        }
    }

    // epilogue: lane holds rows m0+16j+lr, cols 64w+16i+4q+r (r=0..3)
    #pragma unroll
    for (int i = 0; i < 4; i++) {
        int cb = 64 * w + 16 * i + 4 * q;
        float4 bv = *(const float4*)(bias + cb);
        #pragma unroll
        for (int j = 0; j < 4; j++) {
            shortx4 o = {f2bf(acc[i][j][0] + bv.x), f2bf(acc[i][j][1] + bv.y),
                         f2bf(acc[i][j][2] + bv.z), f2bf(acc[i][j][3] + bv.w)};
            *(shortx4*)(outB + (size_t)(m0 + 16 * j + lr) * 1024 + cb * 2) = o;
        }
    }
}

// ---------------------------------------------------------------------------
// Recurrence: 16 WGs x 256 thr (4 waves, 1/SIMD). Wave w owns cols
// [64w,64w+64) = m-tiles 4w..4w+3. C^T = V^T @ h^T per step (32 MFMAs/wave).
// ---------------------------------------------------------------------------
__global__ __launch_bounds__(256, 1)
void rnn_rec(const float* __restrict__ enc, const short* __restrict__ wsV,
             float* __restrict__ out)
{
    __shared__ short hb[2][16 * CHS * 8];   // bf16 h, 16 rows x 33 chunks, x2

    const int tid = threadIdx.x;
    const int w   = tid >> 6;
    const int l   = tid & 63;
    const int lr  = l & 15;
    const int q   = l >> 4;
    const int b0  = blockIdx.x * 16;

    // V^T A-frags: 4 m-tiles x 8 kb (register/AGPR resident).
    short8 vf[4][8];
    #pragma unroll
    for (int i = 0; i < 4; i++)
        #pragma unroll
        for (int kb = 0; kb < 8; kb++)
            vf[i][kb] = *(const short8*)(wsV +
                ((size_t)(kb * 4 + q) * 256 + 64 * w + 16 * i + lr) * 8);

    char* outDecB = (char*)(out + 65536);   // byte base of decoder region

    // init hb[0] = bf16(enc rows b0..b0+15)
    #pragma unroll
    for (int s = 0; s < 2; s++) {
        int ci  = tid * 2 + s;          // 0..511
        int row = ci >> 5;
        int c   = ci & 31;
        const float* g = enc + (size_t)(b0 + row) * HIDn + c * 8;
        float4 g0 = *(const float4*)g;
        float4 g1 = *(const float4*)(g + 4);
        short8 hs = {f2bf(g0.x), f2bf(g0.y), f2bf(g0.z), f2bf(g0.w),
                     f2bf(g1.x), f2bf(g1.y), f2bf(g1.z), f2bf(g1.w)};
        *(short8*)&hb[0][(row * CHS + c) * 8] = hs;
    }

    // XU prefetch, 4 deep: pxu[slot][i] = 4 bf16 (8B) for (row b0+lr, step t)
    const size_t xuRow = (size_t)(b0 + lr) * SEQn;  // in 1KB slots
    uint2 pxu[4][4];
    #pragma unroll
    for (int s = 0; s < 4; s++)
        #pragma unroll
        for (int i = 0; i < 4; i++)
            pxu[s][i] = *(const uint2*)(outDecB + (xuRow + s) * 1024 +
                                        (64 * w + 16 * i + 4 * q) * 2);
    __syncthreads();

    for (int t = 0; t < SEQn; t++) {
        const int cur = t & 1, nxt = cur ^ 1, slot = t & 3;

        // h B-frags (shared across the wave's 4 m-tiles)
        short8 hf[8];
        #pragma unroll
        for (int kb = 0; kb < 8; kb++)
            hf[kb] = *(const short8*)&hb[cur][(lr * CHS + 4 * kb + q) * 8];

        floatx4 acc[4];
        #pragma unroll
        for (int i = 0; i < 4; i++) acc[i] = (floatx4){0.f, 0.f, 0.f, 0.f};
        #pragma unroll
        for (int kb = 0; kb < 8; kb++)
            #pragma unroll
            for (int i = 0; i < 4; i++)
                acc[i] = __builtin_amdgcn_mfma_f32_16x16x32_bf16(
                    vf[i][kb], hf[kb], acc[i], 0, 0, 0);

        // consume prefetched XU for step t, then refill slot with t+4
        uint2 xu[4];
        #pragma unroll
        for (int i = 0; i < 4; i++) xu[i] = pxu[slot][i];
        {
            int tl = (t + 4 < SEQn) ? t + 4 : SEQn - 1;
            #pragma unroll
            for (int i = 0; i < 4; i++)
                pxu[slot][i] = *(const uint2*)(outDecB + (xuRow + tl) * 1024 +
                                               (64 * w + 16 * i + 4 * q) * 2);
        }

        // epilogue: lane holds batch row b0+lr, cols 64w+16i+4q+r
        #pragma unroll
        for (int i = 0; i < 4; i++) {
            float s0 = acc[i][0] + bf2f(xu[i].x & 0xffffu);
            float s1 = acc[i][1] + bf2f(xu[i].x >> 16);
            float s2 = acc[i][2] + bf2f(xu[i].y & 0xffffu);
            float s3 = acc[i][3] + bf2f(xu[i].y >> 16);
            float h0 = 1.f - 2.f / (__expf(2.f * s0) + 1.f);
            float h1 = 1.f - 2.f / (__expf(2.f * s1) + 1.f);
            float h2 = 1.f - 2.f / (__expf(2.f * s2) + 1.f);
            float h3 = 1.f - 2.f / (__expf(2.f * s3) + 1.f);
            // fp32 h -> global (overwrites this row's consumed XU bytes)
            float4 ho = {h0, h1, h2, h3};
            *(float4*)(outDecB + (xuRow + t) * 1024 +
                       (64 * w + 16 * i + 4 * q) * 4) = ho;
            // bf16 h -> hb[nxt]; chunk = 2*(4w+i) + (q>>1), half = q&1
            shortx4 hp = {f2bf(h0), f2bf(h1), f2bf(h2), f2bf(h3)};
            int ch = 2 * (4 * w + i) + (q >> 1);
            *(shortx4*)&hb[nxt][(lr * CHS + ch) * 8 + 4 * (q & 1)] = hp;
        }
        __syncthreads();
    }

    // encoder passthrough (written LAST: weight-scratch fallback lives here)
    #pragma unroll
    for (int j = 0; j < 4; j++) {
        int f   = j * 256 + tid;          // 0..1023
        int row = f >> 6;
        int c4  = f & 63;
        const float4 e = *(const float4*)(enc + (size_t)(b0 + row) * HIDn + c4 * 4);
        *(float4*)(out + (size_t)(b0 + row) * HIDn + c4 * 4) = e;
    }
}

extern "C" void kernel_launch(void* const* d_in, const int* in_sizes, int n_in,
                              void* d_out, int out_size, void* d_ws, size_t ws_size,
                              hipStream_t stream) {
    const float* enc  = (const float*)d_in[0];   // [256,256]
    const float* x    = (const float*)d_in[1];   // [256,512,256]
    const float* U    = (const float*)d_in[2];   // [256,256]
    const float* V    = (const float*)d_in[3];   // [256,256]
    const float* bias = (const float*)d_in[4];   // [256]
    float* out = (float*)d_out;                  // 65536 + 33554432 floats

    // bf16 weight-frag scratch: 128 KB (U) + 128 KB (V); fallback = encoder
    // region of d_out (read early, overwritten only at rnn_rec end).
    short *wsU, *wsV;
    if (ws_size >= 262144) {
        wsU = (short*)d_ws;
        wsV = wsU + 65536;
    } else {
        wsU = (short*)out;
        wsV = wsU + 65536;
    }

    char* outDecB = (char*)(out + 65536);

    prep_W<<<32, 256, 0, stream>>>(U, V, wsU, wsV);
    xu_gemm<<<2048, 256, 0, stream>>>(x, wsU, bias, outDecB);
    rnn_rec<<<16, 256, 0, stream>>>(enc, wsV, out);
}